// Round 3
// baseline (37.653 us; speedup 1.0000x reference)
//
#include <hip/hip_runtime.h>
#include <math.h>

#define NUM_CLASSES 15
#define NUM_ANCHORS 18
#define NC6 21            // NUM_CLASSES + 6
#define GRID 64
#define BATCH 16
#define ROWS 4            // y-rows per block

typedef float f32x4 __attribute__((ext_vector_type(4)));

__device__ __forceinline__ float sigmoidf_fast(float v) {
    return 1.0f / (1.0f + __expf(-v));
}

// One block per (b, a, y0..y0+3) group: 21 channels x 4 rows x 64 x-values.
// q in [0,1344): c = q>>6 (wave-uniform), rr = (q>>4)&3, xs = (q&15)*4.
// Input:  in[((b*378 + a*21 + c)*64 + y)*64 + x]   (c stride = 4096 floats)
// Output: out[(b*73728 + a*4096 + y*64 + x)*21 + c] (c contiguous)
__launch_bounds__(256)
__global__ void yolo_layer_kernel(const float* __restrict__ in,
                                  const float* __restrict__ anchors,
                                  float* __restrict__ out) {
    const int gid = blockIdx.x;                 // 0 .. 16*18*16-1
    const int y4  = gid & 15;
    const int a   = (gid >> 4) % NUM_ANCHORS;
    const int b   = gid / (16 * NUM_ANCHORS);
    const int y0  = y4 * ROWS;

    __shared__ float lds[ROWS * GRID * NC6];    // 5376 floats = 21504 B

    const float aw8 = anchors[a * 3 + 0] * 8.0f;
    const float ah8 = anchors[a * 3 + 1] * 8.0f;
    const float aa  = anchors[a * 3 + 2];

    const int base_in  = (b * (NUM_ANCHORS * NC6) + a * NC6) * (GRID * GRID) + y0 * GRID;
    const int base_out = (b * (NUM_ANCHORS * GRID * GRID) + a * (GRID * GRID) + y0 * GRID) * NC6;

    const int t = threadIdx.x;

    // ---- load + transform + LDS transpose scatter: 1344 float4 per block ----
    #pragma unroll
    for (int i = 0; i < 6; ++i) {
        int q = i * 256 + t;
        if (q < (NC6 * ROWS * GRID / 4)) {      // 1344
            int c  = q >> 6;                    // wave-uniform channel
            int rr = (q >> 4) & 3;              // row within group
            int xs = (q & 15) << 2;
            const float* p = in + base_in + c * (GRID * GRID) + rr * GRID + xs;
            f32x4 v = __builtin_nontemporal_load(reinterpret_cast<const f32x4*>(p));
            float fy = (float)(y0 + rr);
            #pragma unroll
            for (int k = 0; k < 4; ++k) {
                float vk = v[k];
                float r;
                if (c >= 5) {
                    r = sigmoidf_fast(vk);                                   // conf + cls
                } else if (c == 0) {
                    r = (sigmoidf_fast(vk) * 1.05f - 0.025f + (float)(xs + k)) * 8.0f;
                } else if (c == 1) {
                    r = (sigmoidf_fast(vk) * 1.05f - 0.025f + fy) * 8.0f;
                } else if (c == 2) {
                    r = __expf(vk) * aw8;
                } else if (c == 3) {
                    r = __expf(vk) * ah8;
                } else {                                                     // c == 4
                    r = vk + aa;
                }
                lds[(rr * GRID + xs + k) * NC6 + c] = r;
            }
        }
    }
    __syncthreads();

    // ---- contiguous coalesced float4 streaming store of the whole group ----
    #pragma unroll
    for (int i = 0; i < 6; ++i) {
        int q = i * 256 + t;
        if (q < (NC6 * ROWS * GRID / 4)) {      // 1344
            f32x4 v = *reinterpret_cast<const f32x4*>(&lds[q * 4]);
            __builtin_nontemporal_store(v, reinterpret_cast<f32x4*>(out + base_out + q * 4));
        }
    }
}

extern "C" void kernel_launch(void* const* d_in, const int* in_sizes, int n_in,
                              void* d_out, int out_size, void* d_ws, size_t ws_size,
                              hipStream_t stream) {
    const float* in      = (const float*)d_in[0];
    const float* anchors = (const float*)d_in[1];
    float* out           = (float*)d_out;

    const int n_groups = BATCH * NUM_ANCHORS * (GRID / ROWS);   // 4608
    yolo_layer_kernel<<<dim3(n_groups), dim3(256), 0, stream>>>(in, anchors, out);
}